// Round 24
// baseline (103.091 us; speedup 1.0000x reference)
//
#include <hip/hip_runtime.h>
#include <math.h>

#define Bn 16
#define Cn 64
#define Hn 192
#define Wn 192
#define NPIX (Bn * Cn * Hn * Wn)   // 37748736
#define NBLKS 512
#define WCOLS 98
#define SLOTB (WCOLS * 128)        // 12544 B per window row-slot

typedef short bf16x8 __attribute__((ext_vector_type(8)));
typedef float f32x16 __attribute__((ext_vector_type(16)));
typedef __attribute__((address_space(1))) const unsigned int as1_u32;
typedef __attribute__((address_space(3))) unsigned int as3_u32;

// g_Ms[9 slices][64 rows][64 c] bf16; within a row, c-octet g stored at slot (g ^ (p&7)).
__device__ __align__(16) unsigned short g_Ms[9 * 64 * 64];
__device__ __align__(16) float g_b2[64];

static __device__ __forceinline__ unsigned short f2bf(float f) {
    union { float f; unsigned u; } x; x.f = f;
    unsigned r = x.u + 0x7fffu + ((x.u >> 16) & 1u);   // RNE
    return (unsigned short)(r >> 16);
}

__global__ void acdc_precompute(const float* __restrict__ cw, const float* __restrict__ A,
                                const float* __restrict__ D, const float* __restrict__ bias,
                                const int* __restrict__ perm) {
    __shared__ float mre[64];
    int p = blockIdx.x;
    int t = threadIdx.x;
    if (t < 64) {
        float re = 0.f;
        for (int k = 0; k < 64; ++k) {
            int a = (k * t) & 63;
            re += D[k] * cosf((float)a * 0.0981747704246810387f);  // pi/32
        }
        mre[t] = re;
    }
    __syncthreads();
    int pp = perm[p];
    for (int k0 = t; k0 < 576; k0 += 256) {
        int sp = k0 >> 6, c = k0 & 63;
        int g = c >> 3, cil = c & 7;
        float val = 0.f;
        for (int o = 0; o < 8; ++o) {
            int oc = g * 8 + o;
            float gco = mre[(pp - oc + 64) & 63] * A[oc] * (0.125f / 64.0f);
            val += gco * cw[(oc * 8 + cil) * 9 + sp];
        }
        g_Ms[((sp * 64 + p) << 6) + (((g ^ (p & 7)) << 3) | cil)] = f2bf(val);
    }
    if (p == 0 && t < 64)
        g_b2[t] = bias[perm[t]] * 0.125f;
}

// 512 blocks x 1024 thr (16 waves). Block = image x 12-row band x half width.
// WAVE SPECIALIZATION: waves 0-5 compute (32x32x16 MFMA, 2 rows x 3 32px tiles,
// both m-tiles; ~59 regs), waves 6-15 stage (load->ds_write inline, ~24 regs) —
// branch-max keeps kernel under the 64-VGPR cap of 1024-thr builds (R22's spill
// was va/vb+acc live in the SAME thread). 6-slot window, 2-row steps: read slots
// {2t..2t+3}, write slots {2t+4,2t+5} disjoint -> staging overlaps compute,
// ONE barrier per step. M in LDS once. LDS 149 KB.
__global__ __launch_bounds__(1024)
void acdc_main(const float* __restrict__ x, float* __restrict__ out) {
    __shared__ __align__(16) unsigned short Mlds[9 * 64 * 64];   // 73728 B
    __shared__ __align__(16) unsigned char xsb[6 * SLOTB];       // 75264 B

    int tid = threadIdx.x;
    int lane = tid & 63, wv = tid >> 6;   // 16 waves
    // bijective XCD swizzle (512 % 8 == 0)
    int Lb = (blockIdx.x & 7) * (NBLKS / 8) + (blockIdx.x >> 3);
    int bb = Lb >> 5;                 // image
    int band = (Lb >> 1) & 15;        // 12-row band
    int half = Lb & 1;                // width half
    int h0 = band * 12;               // h0 % 6 == 0
    int cbase = half * 96;

    // ---- stage M once: 72 x 1KB chunks, 16 waves ----
    #pragma unroll
    for (int k = 0; k < 5; ++k) {
        int chunk = wv + k * 16;
        if (chunk < 72) {
            const unsigned char* src = (const unsigned char*)g_Ms + chunk * 1024 + lane * 16;
            __builtin_amdgcn_global_load_lds((as1_u32*)(const void*)src,
                (as3_u32*)(void*)((unsigned char*)Mlds + chunk * 1024), 16, 0, 0);
        }
    }

    const float* xb = x + (size_t)bb * Cn * Hn * Wn;

    // ---- prologue: rows h0-1..h0+2 -> slots 0..3 (all threads; fused load+write) ----
    for (int k = 0; k < 4; ++k) {
        int idx = tid + (k << 10);
        if (idx >= 3328) break;
        int cp_lo = idx & 3;
        int f = (idx >> 2) % 26;
        int r4 = idx / 104;
        int rr = r4 & 3, cp_hi = r4 >> 2;
        int cp = cp_hi * 4 + cp_lo;
        int gi = h0 - 1 + rr;
        int gc0 = cbase + 4 * f - 4;
        float av[4] = {0.f,0.f,0.f,0.f}, bv[4] = {0.f,0.f,0.f,0.f};
        bool giok = (unsigned)gi < (unsigned)Hn;
        const float* r0 = xb + ((size_t)(2 * cp) * Hn + (giok ? gi : 0)) * Wn;
        const float* r1 = r0 + Hn * Wn;
        if (giok) {
            if (gc0 >= 0 && gc0 <= Wn - 4) {
                float4 a = *(const float4*)(r0 + gc0);
                float4 b = *(const float4*)(r1 + gc0);
                av[0]=a.x; av[1]=a.y; av[2]=a.z; av[3]=a.w;
                bv[0]=b.x; bv[1]=b.y; bv[2]=b.z; bv[3]=b.w;
            } else {
                #pragma unroll
                for (int j = 0; j < 4; ++j) {
                    int gc = gc0 + j;
                    if ((unsigned)gc < (unsigned)Wn) { av[j] = r0[gc]; bv[j] = r1[gc]; }
                }
            }
        }
        int slot = rr;                       // (gi+1)%6 = rr since h0%6==0
        int chunk = cp >> 2, sub = (cp & 3) * 4;
        #pragma unroll
        for (int j = 0; j < 4; ++j) {
            int c2 = 4 * f + j - 3;
            if ((unsigned)c2 >= (unsigned)WCOLS) continue;
            unsigned u;
            asm("v_cvt_pk_bf16_f32 %0, %1, %2" : "=v"(u) : "v"(av[j]), "v"(bv[j]));
            int key = (c2 + (c2 >> 3) + 3 * slot) & 7;
            *(unsigned*)(xsb + slot * SLOTB + c2 * 128 + ((chunk ^ key) << 4) + sub) = u;
        }
    }
    __syncthreads();   // publishes M + initial 4 rows

    int l31 = lane & 31, lh = lane >> 5;

    for (int t = 0; t < 6; ++t) {
        int hb = h0 + 2 * t;

        if (wv < 6) {
            // ---- compute: wave = (row rr, 32px tile nt); both m-tiles ----
            int rr = wv & 1;
            int nt = wv >> 1;
            f32x16 acc0, acc1;
            #pragma unroll
            for (int e = 0; e < 16; ++e) { acc0[e] = 0.f; acc1[e] = 0.f; }

            #pragma unroll
            for (int sp = 0; sp < 9; ++sp) {
                const int dy = sp / 3, dx = sp % 3;
                int v = 2 * t + rr + dy; if (v >= 6) v -= 6; if (v >= 6) v -= 6;
                int c2 = nt * 32 + l31 + dx;
                int key = (c2 + (c2 >> 3) + 3 * v) & 7;
                const unsigned char* bbase = xsb + v * SLOTB + c2 * 128;
                const unsigned char* abase = (const unsigned char*)Mlds + sp * 8192 + l31 * 128;
                #pragma unroll
                for (int ks = 0; ks < 4; ++ks) {
                    int o = 2 * ks + lh;               // k-octet (channel octet)
                    bf16x8 bfr = *(const bf16x8*)(bbase + ((o ^ key) << 4));
                    const unsigned char* ap = abase + ((o ^ (l31 & 7)) << 4);
                    bf16x8 am0 = *(const bf16x8*)ap;
                    bf16x8 am1 = *(const bf16x8*)(ap + 4096);   // p+32
                    __builtin_amdgcn_s_setprio(1);
                    acc0 = __builtin_amdgcn_mfma_f32_32x32x16_bf16(am0, bfr, acc0, 0, 0, 0);
                    acc1 = __builtin_amdgcn_mfma_f32_32x32x16_bf16(am1, bfr, acc1, 0, 0, 0);
                    __builtin_amdgcn_s_setprio(0);
                }
            }

            // ---- epilogue: +bias; C/D: ch = (r&3)+8*(r>>2)+4*lh, px = l31 ----
            int h = hb + rr;
            int pxg = cbase + nt * 32 + l31;
            #pragma unroll
            for (int r = 0; r < 16; ++r) {
                int chq = (r & 3) + 8 * (r >> 2) + 4 * lh;
                out[(((size_t)(bb * Cn + chq)) * Hn + h) * Wn + pxg]      = acc0[r] + g_b2[chq];
                out[(((size_t)(bb * Cn + 32 + chq)) * Hn + h) * Wn + pxg] = acc1[r] + g_b2[32 + chq];
            }
        } else if (t < 5) {
            // ---- staging waves: rows hb+3, hb+4 -> free slots (2t+4)%6, (2t+5)%6 ----
            for (int k = 0; k < 3; ++k) {
                int sidx = (tid - 384) + k * 640;
                if (sidx >= 1664) break;
                int cp_lo = sidx & 3;
                int f = (sidx >> 2) % 26;
                int r2 = sidx / 104;
                int rr2 = r2 & 1, cp_hi = r2 >> 1;
                int cp = cp_hi * 4 + cp_lo;
                int gi = hb + 3 + rr2;
                int gc0 = cbase + 4 * f - 4;
                float av[4] = {0.f,0.f,0.f,0.f}, bv[4] = {0.f,0.f,0.f,0.f};
                bool giok = (unsigned)gi < (unsigned)Hn;
                const float* r0 = xb + ((size_t)(2 * cp) * Hn + (giok ? gi : 0)) * Wn;
                const float* r1 = r0 + Hn * Wn;
                if (giok) {
                    if (gc0 >= 0 && gc0 <= Wn - 4) {
                        float4 a = *(const float4*)(r0 + gc0);
                        float4 b = *(const float4*)(r1 + gc0);
                        av[0]=a.x; av[1]=a.y; av[2]=a.z; av[3]=a.w;
                        bv[0]=b.x; bv[1]=b.y; bv[2]=b.z; bv[3]=b.w;
                    } else {
                        #pragma unroll
                        for (int j = 0; j < 4; ++j) {
                            int gc = gc0 + j;
                            if ((unsigned)gc < (unsigned)Wn) { av[j] = r0[gc]; bv[j] = r1[gc]; }
                        }
                    }
                }
                int vslot = 2 * t + 4 + rr2; while (vslot >= 6) vslot -= 6;
                int chunk = cp >> 2, sub = (cp & 3) * 4;
                #pragma unroll
                for (int j = 0; j < 4; ++j) {
                    int c2 = 4 * f + j - 3;
                    if ((unsigned)c2 >= (unsigned)WCOLS) continue;
                    unsigned u;
                    asm("v_cvt_pk_bf16_f32 %0, %1, %2" : "=v"(u) : "v"(av[j]), "v"(bv[j]));
                    int key = (c2 + (c2 >> 3) + 3 * vslot) & 7;
                    *(unsigned*)(xsb + vslot * SLOTB + c2 * 128 + ((chunk ^ key) << 4) + sub) = u;
                }
            }
        }

        __syncthreads();   // single barrier: publishes new rows, fences slot reuse
    }
}

extern "C" void kernel_launch(void* const* d_in, const int* in_sizes, int n_in,
                              void* d_out, int out_size, void* d_ws, size_t ws_size,
                              hipStream_t stream) {
    const float* x    = (const float*)d_in[0];
    const float* cw   = (const float*)d_in[1];
    const float* A    = (const float*)d_in[2];
    const float* D    = (const float*)d_in[3];
    const float* bias = (const float*)d_in[4];
    const int*   perm = (const int*)d_in[5];

    acdc_precompute<<<dim3(64), dim3(256), 0, stream>>>(cw, A, D, bias, perm);
    acdc_main<<<dim3(NBLKS), dim3(1024), 0, stream>>>(x, (float*)d_out);
}

// Round 25
// 93.708 us; speedup vs baseline: 1.1001x; 1.1001x over previous
//
#include <hip/hip_runtime.h>
#include <math.h>

#define Bn 16
#define Cn 64
#define Hn 192
#define Wn 192
#define NPIX (Bn * Cn * Hn * Wn)       // 37748736
#define NBLKS 256
#define ROWS 12                        // output rows per block (16 bands x 16 images)
#define SLOTB (194 * 128)              // 24832 B per window row-slot

typedef short bf16x8 __attribute__((ext_vector_type(8)));
typedef float f32x4 __attribute__((ext_vector_type(4)));
typedef __attribute__((address_space(1))) const unsigned int as1_u32;
typedef __attribute__((address_space(3))) unsigned int as3_u32;

// g_Ms[9 slices][64 rows][64 c] bf16; within a row, c-octet g stored at slot (g ^ (p&7)).
__device__ __align__(16) unsigned short g_Ms[9 * 64 * 64];
__device__ __align__(16) float g_b2[64];

static __device__ __forceinline__ unsigned short f2bf(float f) {
    union { float f; unsigned u; } x; x.f = f;
    unsigned r = x.u + 0x7fffu + ((x.u >> 16) & 1u);   // RNE
    return (unsigned short)(r >> 16);
}

__global__ void acdc_precompute(const float* __restrict__ cw, const float* __restrict__ A,
                                const float* __restrict__ D, const float* __restrict__ bias,
                                const int* __restrict__ perm) {
    __shared__ float mre[64];
    int p = blockIdx.x;
    int t = threadIdx.x;
    if (t < 64) {
        float re = 0.f;
        for (int k = 0; k < 64; ++k) {
            int a = (k * t) & 63;
            re += D[k] * cosf((float)a * 0.0981747704246810387f);  // pi/32
        }
        mre[t] = re;
    }
    __syncthreads();
    int pp = perm[p];
    for (int k0 = t; k0 < 576; k0 += 256) {
        int sp = k0 >> 6, c = k0 & 63;
        int g = c >> 3, cil = c & 7;
        float val = 0.f;
        for (int o = 0; o < 8; ++o) {
            int oc = g * 8 + o;
            float gco = mre[(pp - oc + 64) & 63] * A[oc] * (0.125f / 64.0f);
            val += gco * cw[(oc * 8 + cil) * 9 + sp];
        }
        g_Ms[((sp * 64 + p) << 6) + (((g ^ (p & 7)) << 3) | cil)] = f2bf(val);
    }
    if (p == 0 && t < 64)
        g_b2[t] = bias[perm[t]] * 0.125f;
}

// R19 (92us best) byte-exact EXCEPT the staging item map: cp now in the low 2 lane
// bits (R23-proven) so staged dword writes spread across all 32 banks instead of
// ~8 (R19's cp=idx/50 gave ~50 lanes the same chunk/sub -> ~6-way write conflicts,
// 19.6M conflict cycles = ~32us of the 103us profiled run).
__global__ __launch_bounds__(1024)
void acdc_main(const float* __restrict__ x, float* __restrict__ out) {
    __shared__ __align__(16) unsigned short Mlds[9 * 64 * 64];    // 73728 B
    __shared__ __align__(16) unsigned char xsb[3 * SLOTB];        // 74496 B

    int tid = threadIdx.x;
    int lane = tid & 63, wv = tid >> 6;
    // bijective XCD swizzle: each XCD gets 32 consecutive logical blocks = 2 whole images
    int Lb = (blockIdx.x & 7) * (NBLKS / 8) + (blockIdx.x >> 3);
    int bb = Lb >> 4;                 // image
    int h0 = (Lb & 15) * ROWS;        // row band (h0 % 3 == 0 always)

    // ---- stage M once: 72 x 1KB chunks via global_load_lds ----
    #pragma unroll
    for (int k = 0; k < 5; ++k) {
        int chunk = wv + k * 16;
        if (chunk < 72) {
            const unsigned char* src = (const unsigned char*)g_Ms + chunk * 1024 + lane * 16;
            __builtin_amdgcn_global_load_lds((as1_u32*)(const void*)src,
                (as3_u32*)(void*)((unsigned char*)Mlds + chunk * 1024), 16, 0, 0);
        }
    }

    int pxw = lane & 15, q = lane >> 4, rlane = lane & 15;
    int m = wv >> 2;                  // m-tile 0..3 (out channels m*16..m*16+15)
    int ng = wv & 3;                  // n-group: n-tiles ng, ng+4, ng+8

    const float* xb = x + (size_t)bb * Cn * Hn * Wn;

    // ---- x row stage: one input row; cp in LOW 2 bits of lane (bank spread) ----
    float4 va[2], vb[2];
    auto xload = [&](int gh) {
        bool ok = (unsigned)gh < (unsigned)Hn;
        int ghc = ok ? gh : 0;
        #pragma unroll
        for (int k = 0; k < 2; ++k) {
            int idx = tid + (k << 10);
            va[k] = (float4){0.f, 0.f, 0.f, 0.f};
            vb[k] = (float4){0.f, 0.f, 0.f, 0.f};
            if (idx < 1600) {
                int cp_lo = idx & 3;
                int f = (idx >> 2) % 50;
                int cp = (idx / 200) * 4 + cp_lo;
                if (ok && f >= 1 && f <= 48) {
                    const float* r0 = xb + ((size_t)(2 * cp) * Hn + ghc) * Wn + (f * 4 - 4);
                    va[k] = *(const float4*)r0;
                    vb[k] = *(const float4*)(r0 + Hn * Wn);
                }
            }
        }
    };
    auto xwrite = [&](int slot) {
        #pragma unroll
        for (int k = 0; k < 2; ++k) {
            int idx = tid + (k << 10);
            if (idx >= 1600) break;
            int cp_lo = idx & 3;
            int f = (idx >> 2) % 50;
            int cp = (idx / 200) * 4 + cp_lo;
            int chunk = cp >> 2, sub = (cp & 3) * 4;
            float v0[4] = {va[k].x, va[k].y, va[k].z, va[k].w};
            float v1[4] = {vb[k].x, vb[k].y, vb[k].z, vb[k].w};
            #pragma unroll
            for (int j = 0; j < 4; ++j) {
                int c2 = f * 4 - 3 + j;            // window col = global col + 1
                if ((unsigned)c2 >= 194u) continue;
                unsigned u;
                asm("v_cvt_pk_bf16_f32 %0, %1, %2" : "=v"(u) : "v"(v0[j]), "v"(v1[j]));
                int key = (c2 + (c2 >> 3) + 3 * slot) & 7;
                int byte = slot * SLOTB + c2 * 128 + ((chunk ^ key) << 4) + sub;
                *(unsigned*)(xsb + byte) = u;
            }
        }
    };

    // prologue: rows h0-1, h0, h0+1 -> slots 0,1,2  (slot(gh) = (gh+1)%3, h0%3==0)
    xload(h0 - 1); xwrite(0);
    xload(h0);     xwrite(1);
    xload(h0 + 1); xwrite(2);
    __syncthreads();   // publishes M + initial window

    int sA = 0;        // slot of gh = h-1  (== t % 3)
    for (int t = 0; t < ROWS; ++t) {
        int h = h0 + t;
        int sB = sA + 1; if (sB == 3) sB = 0;
        int sC = sB + 1; if (sC == 3) sC = 0;
        if (t < ROWS - 1) xload(h + 2);   // issue next row's loads; retire under compute

        f32x4 acc[3];
        #pragma unroll
        for (int i = 0; i < 3; ++i) acc[i] = (f32x4){0.f, 0.f, 0.f, 0.f};

        #pragma unroll
        for (int sp = 0; sp < 9; ++sp) {
            const int dy = sp / 3, dx = sp % 3;
            int slotr = (dy == 0) ? sA : (dy == 1) ? sB : sC;
            int sb = slotr * SLOTB;
            int s3 = 3 * slotr;
            int c2b = ng * 16 + pxw + dx;
            #pragma unroll
            for (int kh = 0; kh < 2; ++kh) {
                int ksl = kh * 4 + q;
                bf16x8 am = *(const bf16x8*)((const unsigned char*)Mlds + sp * 8192 +
                             rlane * 128 + ((ksl ^ (rlane & 7)) << 4) + m * 2048);
                bf16x8 bfr[3];
                #pragma unroll
                for (int i = 0; i < 3; ++i) {
                    int c2 = c2b + i * 64;
                    int key = (c2 + (c2 >> 3) + s3) & 7;
                    bfr[i] = *(const bf16x8*)(xsb + sb + c2 * 128 + ((ksl ^ key) << 4));
                }
                __builtin_amdgcn_s_setprio(1);
                #pragma unroll
                for (int i = 0; i < 3; ++i)
                    acc[i] = __builtin_amdgcn_mfma_f32_16x16x32_bf16(am, bfr[i], acc[i], 0, 0, 0);
                __builtin_amdgcn_s_setprio(0);
            }
        }

        // ---- epilogue: +bias; full-width coalesced row stores ----
        {
            int rbase = m * 16 + q * 4;
            float4 bq = *(const float4*)(g_b2 + rbase);
            float bvs[4] = {bq.x, bq.y, bq.z, bq.w};
            #pragma unroll
            for (int i = 0; i < 3; ++i) {
                int px = (ng + i * 4) * 16 + pxw;
                #pragma unroll
                for (int j = 0; j < 4; ++j)
                    out[(((size_t)(bb * Cn + rbase + j)) * Hn + h) * Wn + px] =
                        acc[i][j] + bvs[j];
            }
        }

        __syncthreads();                  // all window reads for row h done
        if (t < ROWS - 1) xwrite(sA);     // row h+2 -> slot (h+3)%3 == sA
        __syncthreads();                  // publish new row
        sA = sB;
    }
}

extern "C" void kernel_launch(void* const* d_in, const int* in_sizes, int n_in,
                              void* d_out, int out_size, void* d_ws, size_t ws_size,
                              hipStream_t stream) {
    const float* x    = (const float*)d_in[0];
    const float* cw   = (const float*)d_in[1];
    const float* A    = (const float*)d_in[2];
    const float* D    = (const float*)d_in[3];
    const float* bias = (const float*)d_in[4];
    const int*   perm = (const int*)d_in[5];

    acdc_precompute<<<dim3(64), dim3(256), 0, stream>>>(cw, A, D, bias, perm);
    acdc_main<<<dim3(NBLKS), dim3(1024), 0, stream>>>(x, (float*)d_out);
}